// Round 1
// baseline (605.730 us; speedup 1.0000x reference)
//
#include <hip/hip_runtime.h>

#define DIM 128
#define EPS 1e-5f
#define WAVES_PER_BLOCK 4

// One wave (64 lanes) per destination node. Lane i handles dims {2i, 2i+1}.
// edge_row is sorted, so each node's incoming edges are a contiguous range
// found by binary search -> no atomics, no workspace, single kernel.
__global__ __launch_bounds__(WAVES_PER_BLOCK * 64)
void gnn_fused_kernel(const float* __restrict__ x,
                      const int*   __restrict__ edge_row,
                      const int*   __restrict__ edge_col,
                      const float* __restrict__ edge_val,
                      const float* __restrict__ gamma,
                      const float* __restrict__ beta,
                      float*       __restrict__ out,
                      int n_nodes, int n_edges)
{
    const int wave = threadIdx.x >> 6;
    const int lane = threadIdx.x & 63;
    const int node = blockIdx.x * WAVES_PER_BLOCK + wave;
    if (node >= n_nodes) return;

    // --- binary search: start = lower_bound(edge_row, node),
    //                    end   = lower_bound(edge_row, node+1)
    int lo = 0, hi = n_edges;
    while (lo < hi) {
        int mid = (lo + hi) >> 1;
        if (edge_row[mid] < node) lo = mid + 1; else hi = mid;
    }
    const int start = lo;
    hi = n_edges;                    // lo already >= start
    while (lo < hi) {
        int mid = (lo + hi) >> 1;
        if (edge_row[mid] <= node) lo = mid + 1; else hi = mid;
    }
    const int end = lo;

    const float2* __restrict__ x2 = (const float2*)x;

    // --- segment sum: acc = sum_e val[e] * x[col[e]]
    float accx = 0.f, accy = 0.f;
    for (int e = start; e < end; ++e) {
        const int   col = edge_col[e];
        const float val = edge_val[e];
        const float2 v  = x2[col * (DIM / 2) + lane];
        accx = fmaf(val, v.x, accx);
        accy = fmaf(val, v.y, accy);
    }

    // --- residual
    const float2 xv = x2[node * (DIM / 2) + lane];
    const float h0 = accx + xv.x;
    const float h1 = accy + xv.y;

    // --- layernorm over 128 dims via wave-wide shuffle reduction
    float s  = h0 + h1;
    float sq = h0 * h0 + h1 * h1;
#pragma unroll
    for (int off = 32; off > 0; off >>= 1) {
        s  += __shfl_xor(s,  off, 64);
        sq += __shfl_xor(sq, off, 64);
    }
    const float mean = s * (1.0f / (float)DIM);
    const float var  = sq * (1.0f / (float)DIM) - mean * mean;
    const float rs   = rsqrtf(var + EPS);

    const float2 g = ((const float2*)gamma)[lane];
    const float2 b = ((const float2*)beta)[lane];
    float2 o;
    o.x = (h0 - mean) * rs * g.x + b.x;
    o.y = (h1 - mean) * rs * g.y + b.y;
    ((float2*)out)[node * (DIM / 2) + lane] = o;
}

extern "C" void kernel_launch(void* const* d_in, const int* in_sizes, int n_in,
                              void* d_out, int out_size, void* d_ws, size_t ws_size,
                              hipStream_t stream)
{
    const float* x        = (const float*)d_in[0];
    const int*   edge_row = (const int*)  d_in[1];
    const int*   edge_col = (const int*)  d_in[2];
    const float* edge_val = (const float*)d_in[3];
    const float* gamma    = (const float*)d_in[4];
    const float* beta     = (const float*)d_in[5];
    float*       out      = (float*)d_out;

    const int n_nodes = in_sizes[0] / DIM;   // 100000
    const int n_edges = in_sizes[1];         // 3200000

    const int blocks = (n_nodes + WAVES_PER_BLOCK - 1) / WAVES_PER_BLOCK;
    gnn_fused_kernel<<<blocks, WAVES_PER_BLOCK * 64, 0, stream>>>(
        x, edge_row, edge_col, edge_val, gamma, beta, out, n_nodes, n_edges);
}

// Round 2
// 338.060 us; speedup vs baseline: 1.7918x; 1.7918x over previous
//
#include <hip/hip_runtime.h>

#define DIM 128
#define EPS 1e-5f
#define WAVES_PER_BLOCK 4
#define UNROLL 8

// ---------------------------------------------------------------------------
// Kernel 1: build CSR row_ptr from sorted edge_row.
// row_ptr[r] = lower_bound(edge_row, r); row_ptr[N] = n_edges.
// Thread e fills rows (edge_row[e-1], edge_row[e]]; thread 0 fills the head,
// the last thread fills the tail. Every row 0..N written exactly once.
// ---------------------------------------------------------------------------
__global__ void build_row_ptr(const int* __restrict__ edge_row,
                              int* __restrict__ row_ptr,
                              int n_nodes, int n_edges)
{
    int e = blockIdx.x * blockDim.x + threadIdx.x;
    if (e >= n_edges) return;
    int cur  = edge_row[e];
    int prev = (e == 0) ? -1 : edge_row[e - 1];
    for (int r = prev + 1; r <= cur; ++r) row_ptr[r] = e;
    if (e == n_edges - 1) {
        for (int r = cur + 1; r <= n_nodes; ++r) row_ptr[r] = n_edges;
    }
}

// ---------------------------------------------------------------------------
// Kernel 2: one wave per node; lane i owns dims {2i, 2i+1}.
// Edge loop batched UNROLL-deep so UNROLL independent 512B gathers are in
// flight per wave (the R1 version had ~1: VGPR_Count=12, latency-bound).
// ---------------------------------------------------------------------------
__global__ __launch_bounds__(WAVES_PER_BLOCK * 64)
void gnn_fused_kernel(const float* __restrict__ x,
                      const int*   __restrict__ row_ptr,
                      const int*   __restrict__ edge_col,
                      const float* __restrict__ edge_val,
                      const float* __restrict__ gamma,
                      const float* __restrict__ beta,
                      float*       __restrict__ out,
                      int n_nodes)
{
    const int wave = threadIdx.x >> 6;
    const int lane = threadIdx.x & 63;
    const int node = blockIdx.x * WAVES_PER_BLOCK + wave;
    if (node >= n_nodes) return;

    const int start = row_ptr[node];
    const int end   = row_ptr[node + 1];

    const float2* __restrict__ x2 = (const float2*)x;

    float accx = 0.f, accy = 0.f;

    int e = start;
    // main batched loop: UNROLL independent gathers in flight
    for (; e + UNROLL <= end; e += UNROLL) {
        int   c[UNROLL];
        float w[UNROLL];
#pragma unroll
        for (int u = 0; u < UNROLL; ++u) {
            c[u] = edge_col[e + u];
            w[u] = edge_val[e + u];
        }
        float2 v[UNROLL];
#pragma unroll
        for (int u = 0; u < UNROLL; ++u)
            v[u] = x2[c[u] * (DIM / 2) + lane];
#pragma unroll
        for (int u = 0; u < UNROLL; ++u) {
            accx = fmaf(w[u], v[u].x, accx);
            accy = fmaf(w[u], v[u].y, accy);
        }
    }
    // tail
    for (; e < end; ++e) {
        const int   col = edge_col[e];
        const float val = edge_val[e];
        const float2 v  = x2[col * (DIM / 2) + lane];
        accx = fmaf(val, v.x, accx);
        accy = fmaf(val, v.y, accy);
    }

    // residual
    const float2 xv = x2[node * (DIM / 2) + lane];
    const float h0 = accx + xv.x;
    const float h1 = accy + xv.y;

    // layernorm over 128 dims via wave-wide shuffle reduction
    float s  = h0 + h1;
    float sq = h0 * h0 + h1 * h1;
#pragma unroll
    for (int off = 32; off > 0; off >>= 1) {
        s  += __shfl_xor(s,  off, 64);
        sq += __shfl_xor(sq, off, 64);
    }
    const float mean = s * (1.0f / (float)DIM);
    const float var  = sq * (1.0f / (float)DIM) - mean * mean;
    const float rs   = rsqrtf(var + EPS);

    const float2 g = ((const float2*)gamma)[lane];
    const float2 b = ((const float2*)beta)[lane];
    float2 o;
    o.x = (h0 - mean) * rs * g.x + b.x;
    o.y = (h1 - mean) * rs * g.y + b.y;
    ((float2*)out)[node * (DIM / 2) + lane] = o;
}

extern "C" void kernel_launch(void* const* d_in, const int* in_sizes, int n_in,
                              void* d_out, int out_size, void* d_ws, size_t ws_size,
                              hipStream_t stream)
{
    const float* x        = (const float*)d_in[0];
    const int*   edge_row = (const int*)  d_in[1];
    const int*   edge_col = (const int*)  d_in[2];
    const float* edge_val = (const float*)d_in[3];
    const float* gamma    = (const float*)d_in[4];
    const float* beta     = (const float*)d_in[5];
    float*       out      = (float*)d_out;

    const int n_nodes = in_sizes[0] / DIM;   // 100000
    const int n_edges = in_sizes[1];         // 3200000

    int* row_ptr = (int*)d_ws;               // (n_nodes+1) ints

    build_row_ptr<<<(n_edges + 255) / 256, 256, 0, stream>>>(
        edge_row, row_ptr, n_nodes, n_edges);

    const int blocks = (n_nodes + WAVES_PER_BLOCK - 1) / WAVES_PER_BLOCK;
    gnn_fused_kernel<<<blocks, WAVES_PER_BLOCK * 64, 0, stream>>>(
        x, row_ptr, edge_col, edge_val, gamma, beta, out, n_nodes);
}

// Round 3
// 290.342 us; speedup vs baseline: 2.0863x; 1.1644x over previous
//
#include <hip/hip_runtime.h>
#include <hip/hip_fp16.h>

#define DIM 128
#define EPS 1e-5f
#define WAVES_PER_BLOCK 4
#define UNROLL 16

// ---------------------------------------------------------------------------
// Kernel 1: build CSR row_ptr from sorted edge_row.
// ---------------------------------------------------------------------------
__global__ void build_row_ptr(const int* __restrict__ edge_row,
                              int* __restrict__ row_ptr,
                              int n_nodes, int n_edges)
{
    int e = blockIdx.x * blockDim.x + threadIdx.x;
    if (e >= n_edges) return;
    int cur  = edge_row[e];
    int prev = (e == 0) ? -1 : edge_row[e - 1];
    for (int r = prev + 1; r <= cur; ++r) row_ptr[r] = e;
    if (e == n_edges - 1) {
        for (int r = cur + 1; r <= n_nodes; ++r) row_ptr[r] = n_edges;
    }
}

// ---------------------------------------------------------------------------
// Kernel 2: convert x (fp32) -> x_half (fp16) for the gather path.
// Each thread: 4 floats in (float4), 4 halves out (uint2 = 2x half2).
// ---------------------------------------------------------------------------
__global__ void convert_x_half(const float4* __restrict__ x4,
                               __half2* __restrict__ xh2,
                               int n4)  // n4 = N*DIM/4
{
    int i = blockIdx.x * blockDim.x + threadIdx.x;
    if (i >= n4) return;
    float4 v = x4[i];
    xh2[2 * i]     = __float22half2_rn(make_float2(v.x, v.y));
    xh2[2 * i + 1] = __float22half2_rn(make_float2(v.z, v.w));
}

// ---------------------------------------------------------------------------
// Kernel 3: one wave per node; lane i owns dims {2i, 2i+1}.
// Gather reads fp16 rows (256B/wave, halves L2-miss bytes AND fits the
// 25.6MB x_half working set near aggregate-L2 capacity). Accumulate fp32.
// Residual + epilogue use fp32 x for precision.
// ---------------------------------------------------------------------------
__global__ __launch_bounds__(WAVES_PER_BLOCK * 64)
void gnn_fused_kernel(const float* __restrict__ x,
                      const __half2* __restrict__ xh2,
                      const int*   __restrict__ row_ptr,
                      const int*   __restrict__ edge_col,
                      const float* __restrict__ edge_val,
                      const float* __restrict__ gamma,
                      const float* __restrict__ beta,
                      float*       __restrict__ out,
                      int n_nodes)
{
    const int wave = threadIdx.x >> 6;
    const int lane = threadIdx.x & 63;
    const int node = blockIdx.x * WAVES_PER_BLOCK + wave;
    if (node >= n_nodes) return;

    const int start = row_ptr[node];
    const int end   = row_ptr[node + 1];

    float accx = 0.f, accy = 0.f;

    int e = start;
    for (; e + UNROLL <= end; e += UNROLL) {
        int   c[UNROLL];
        float w[UNROLL];
#pragma unroll
        for (int u = 0; u < UNROLL; ++u) {
            c[u] = edge_col[e + u];
            w[u] = edge_val[e + u];
        }
        __half2 v[UNROLL];
#pragma unroll
        for (int u = 0; u < UNROLL; ++u)
            v[u] = xh2[c[u] * (DIM / 2) + lane];
#pragma unroll
        for (int u = 0; u < UNROLL; ++u) {
            float2 f = __half22float2(v[u]);
            accx = fmaf(w[u], f.x, accx);
            accy = fmaf(w[u], f.y, accy);
        }
    }
    for (; e < end; ++e) {
        const int   col = edge_col[e];
        const float val = edge_val[e];
        float2 f = __half22float2(xh2[col * (DIM / 2) + lane]);
        accx = fmaf(val, f.x, accx);
        accy = fmaf(val, f.y, accy);
    }

    // residual (full fp32)
    const float2 xv = ((const float2*)x)[node * (DIM / 2) + lane];
    const float h0 = accx + xv.x;
    const float h1 = accy + xv.y;

    // layernorm via wave-wide shuffle reduction
    float s  = h0 + h1;
    float sq = h0 * h0 + h1 * h1;
#pragma unroll
    for (int off = 32; off > 0; off >>= 1) {
        s  += __shfl_xor(s,  off, 64);
        sq += __shfl_xor(sq, off, 64);
    }
    const float mean = s * (1.0f / (float)DIM);
    const float var  = sq * (1.0f / (float)DIM) - mean * mean;
    const float rs   = rsqrtf(var + EPS);

    const float2 g = ((const float2*)gamma)[lane];
    const float2 b = ((const float2*)beta)[lane];
    float2 o;
    o.x = (h0 - mean) * rs * g.x + b.x;
    o.y = (h1 - mean) * rs * g.y + b.y;
    ((float2*)out)[node * (DIM / 2) + lane] = o;
}

extern "C" void kernel_launch(void* const* d_in, const int* in_sizes, int n_in,
                              void* d_out, int out_size, void* d_ws, size_t ws_size,
                              hipStream_t stream)
{
    const float* x        = (const float*)d_in[0];
    const int*   edge_row = (const int*)  d_in[1];
    const int*   edge_col = (const int*)  d_in[2];
    const float* edge_val = (const float*)d_in[3];
    const float* gamma    = (const float*)d_in[4];
    const float* beta     = (const float*)d_in[5];
    float*       out      = (float*)d_out;

    const int n_nodes = in_sizes[0] / DIM;   // 100000
    const int n_edges = in_sizes[1];         // 3200000
    const int n_elem  = in_sizes[0];         // N*DIM

    // workspace layout: [x_half: n_elem*2 bytes][row_ptr: (n_nodes+1)*4 bytes]
    __half2* xh2     = (__half2*)d_ws;
    int*     row_ptr = (int*)((char*)d_ws + (size_t)n_elem * sizeof(__half));

    build_row_ptr<<<(n_edges + 255) / 256, 256, 0, stream>>>(
        edge_row, row_ptr, n_nodes, n_edges);

    const int n4 = n_elem / 4;
    convert_x_half<<<(n4 + 255) / 256, 256, 0, stream>>>(
        (const float4*)x, xh2, n4);

    const int blocks = (n_nodes + WAVES_PER_BLOCK - 1) / WAVES_PER_BLOCK;
    gnn_fused_kernel<<<blocks, WAVES_PER_BLOCK * 64, 0, stream>>>(
        x, xh2, row_ptr, edge_col, edge_val, gamma, beta, out, n_nodes);
}

// Round 4
// 249.823 us; speedup vs baseline: 2.4246x; 1.1622x over previous
//
#include <hip/hip_runtime.h>
#include <hip/hip_fp16.h>

#define DIM 128
#define EPS 1e-5f
#define WAVES_PER_BLOCK 4
#define UNROLL 16

// ---------------------------------------------------------------------------
// Prep kernel (fused): thread i converts 4 floats of x -> fp16, and fills
// CSR row_ptr from sorted edge_row (thread e covers rows (row[e-1], row[e]]).
// ---------------------------------------------------------------------------
__global__ void prep_kernel(const float4* __restrict__ x4,
                            __half2* __restrict__ xh2,
                            const int* __restrict__ edge_row,
                            int* __restrict__ row_ptr,
                            int n4, int n_nodes, int n_edges)
{
    int i = blockIdx.x * blockDim.x + threadIdx.x;
    if (i < n4) {
        float4 v = x4[i];
        xh2[2 * i]     = __float22half2_rn(make_float2(v.x, v.y));
        xh2[2 * i + 1] = __float22half2_rn(make_float2(v.z, v.w));
    }
    if (i < n_edges) {
        int cur  = edge_row[i];
        int prev = (i == 0) ? -1 : edge_row[i - 1];
        for (int r = prev + 1; r <= cur; ++r) row_ptr[r] = i;
        if (i == n_edges - 1) {
            for (int r = cur + 1; r <= n_nodes; ++r) row_ptr[r] = n_edges;
        }
    }
}

// ---------------------------------------------------------------------------
// Main kernel: one wave per node; lane i owns dims {2i, 2i+1} (half2 = 4B).
// Edge loop is FULLY predicated into aligned 16-deep batches:
//   - no serial tail (the R3 latency sink)
//   - edge ids/vals loaded as broadcast int4/float4 (8 VMEM/batch, not 32)
//   - masked slots gather hot row 0 with w=0 (free in L1/L2)
// ---------------------------------------------------------------------------
__global__ __launch_bounds__(WAVES_PER_BLOCK * 64)
void gnn_fused_kernel(const __half2* __restrict__ xh2,
                      const int*   __restrict__ row_ptr,
                      const int*   __restrict__ edge_col,
                      const float* __restrict__ edge_val,
                      const float* __restrict__ gamma,
                      const float* __restrict__ beta,
                      float*       __restrict__ out,
                      int n_nodes, int n_edges)
{
    const int wave = threadIdx.x >> 6;
    const int lane = threadIdx.x & 63;
    const int node = blockIdx.x * WAVES_PER_BLOCK + wave;
    if (node >= n_nodes) return;

    const int start = row_ptr[node];
    const int end   = row_ptr[node + 1];
    const unsigned len = (unsigned)(end - start);

    float accx = 0.f, accy = 0.f;

    const int ebase = start & ~3;          // 4-aligned for int4/float4 loads
    for (int e0 = ebase; e0 < end; e0 += UNROLL) {
        int   c[UNROLL];
        float w[UNROLL];
        // broadcast vector loads of edge data (wave-uniform addresses)
#pragma unroll
        for (int u4 = 0; u4 < UNROLL / 4; ++u4) {
            int b  = e0 + 4 * u4;
            int bb = (b < n_edges) ? b : 0;     // clamp: never read OOB
            int4   c4 = *(const int4*)  (edge_col + bb);
            float4 w4 = *(const float4*)(edge_val + bb);
            c[4 * u4 + 0] = c4.x; c[4 * u4 + 1] = c4.y;
            c[4 * u4 + 2] = c4.z; c[4 * u4 + 3] = c4.w;
            w[4 * u4 + 0] = w4.x; w[4 * u4 + 1] = w4.y;
            w[4 * u4 + 2] = w4.z; w[4 * u4 + 3] = w4.w;
        }
        // predicate out-of-range slots (head alignment + tail)
#pragma unroll
        for (int u = 0; u < UNROLL; ++u) {
            bool in = (unsigned)(e0 + u - start) < len;
            c[u] = in ? c[u] : 0;
            w[u] = in ? w[u] : 0.f;
        }
        // 16 independent gathers in flight
        __half2 v[UNROLL];
#pragma unroll
        for (int u = 0; u < UNROLL; ++u)
            v[u] = xh2[c[u] * (DIM / 2) + lane];
#pragma unroll
        for (int u = 0; u < UNROLL; ++u) {
            float2 f = __half22float2(v[u]);
            accx = fmaf(w[u], f.x, accx);
            accy = fmaf(w[u], f.y, accy);
        }
    }

    // residual (fp16 copy — x fp32 no longer touched by this kernel)
    const float2 xv = __half22float2(xh2[node * (DIM / 2) + lane]);
    const float h0 = accx + xv.x;
    const float h1 = accy + xv.y;

    // layernorm via wave-wide shuffle reduction
    float s  = h0 + h1;
    float sq = h0 * h0 + h1 * h1;
#pragma unroll
    for (int off = 32; off > 0; off >>= 1) {
        s  += __shfl_xor(s,  off, 64);
        sq += __shfl_xor(sq, off, 64);
    }
    const float mean = s * (1.0f / (float)DIM);
    const float var  = sq * (1.0f / (float)DIM) - mean * mean;
    const float rs   = rsqrtf(var + EPS);

    const float2 g = ((const float2*)gamma)[lane];
    const float2 b = ((const float2*)beta)[lane];
    float2 o;
    o.x = (h0 - mean) * rs * g.x + b.x;
    o.y = (h1 - mean) * rs * g.y + b.y;
    ((float2*)out)[node * (DIM / 2) + lane] = o;
}

extern "C" void kernel_launch(void* const* d_in, const int* in_sizes, int n_in,
                              void* d_out, int out_size, void* d_ws, size_t ws_size,
                              hipStream_t stream)
{
    const float* x        = (const float*)d_in[0];
    const int*   edge_row = (const int*)  d_in[1];
    const int*   edge_col = (const int*)  d_in[2];
    const float* edge_val = (const float*)d_in[3];
    const float* gamma    = (const float*)d_in[4];
    const float* beta     = (const float*)d_in[5];
    float*       out      = (float*)d_out;

    const int n_nodes = in_sizes[0] / DIM;   // 100000
    const int n_edges = in_sizes[1];         // 3200000
    const int n_elem  = in_sizes[0];         // N*DIM
    const int n4      = n_elem / 4;

    // workspace: [x_half: n_elem*2 B][row_ptr: (n_nodes+1)*4 B]
    __half2* xh2     = (__half2*)d_ws;
    int*     row_ptr = (int*)((char*)d_ws + (size_t)n_elem * sizeof(__half));

    int prep_threads = (n4 > n_edges) ? n4 : n_edges;
    prep_kernel<<<(prep_threads + 255) / 256, 256, 0, stream>>>(
        (const float4*)x, xh2, edge_row, row_ptr, n4, n_nodes, n_edges);

    const int blocks = (n_nodes + WAVES_PER_BLOCK - 1) / WAVES_PER_BLOCK;
    gnn_fused_kernel<<<blocks, WAVES_PER_BLOCK * 64, 0, stream>>>(
        xh2, row_ptr, edge_col, edge_val, gamma, beta, out, n_nodes, n_edges);
}

// Round 5
// 235.673 us; speedup vs baseline: 2.5702x; 1.0600x over previous
//
#include <hip/hip_runtime.h>
#include <hip/hip_fp16.h>

#define DIM 128
#define EPS 1e-5f
#define WPB 4            // waves per block
#define UF  4            // unrolled iterations -> 16 edges in flight per wave

// ---------------------------------------------------------------------------
// Prep kernel (fused): convert x fp32 -> fp16, build CSR row_ptr from the
// sorted edge_row (thread e covers rows (row[e-1], row[e]]).
// ---------------------------------------------------------------------------
__global__ void prep_kernel(const float4* __restrict__ x4,
                            __half2* __restrict__ xh2,
                            const int* __restrict__ edge_row,
                            int* __restrict__ row_ptr,
                            int n4, int n_nodes, int n_edges)
{
    int i = blockIdx.x * blockDim.x + threadIdx.x;
    if (i < n4) {
        float4 v = x4[i];
        xh2[2 * i]     = __float22half2_rn(make_float2(v.x, v.y));
        xh2[2 * i + 1] = __float22half2_rn(make_float2(v.z, v.w));
    }
    if (i < n_edges) {
        int cur  = edge_row[i];
        int prev = (i == 0) ? -1 : edge_row[i - 1];
        for (int r = prev + 1; r <= cur; ++r) row_ptr[r] = i;
        if (i == n_edges - 1) {
            for (int r = cur + 1; r <= n_nodes; ++r) row_ptr[r] = n_edges;
        }
    }
}

// ---------------------------------------------------------------------------
// Main kernel: one wave per node, split into 4 quarter-waves.
//   q   = lane>>4  : which of 4 edges this lane works on per iteration
//   sub = lane&15  : dim group [sub*8, sub*8+8), loaded as half8 = 16B
// One wave-iteration processes 4 edges: 1 gather inst = 1024B (4 full rows),
// predication/addressing amortized 4-ways. ~4-5 VALU inst/edge vs R4's ~9.
// ---------------------------------------------------------------------------
__global__ __launch_bounds__(WPB * 64)
void gnn_fused_kernel(const uint4* __restrict__ xh16,   // fp16 x, 16B units
                      const int*   __restrict__ row_ptr,
                      const int*   __restrict__ edge_col,
                      const float* __restrict__ edge_val,
                      const float* __restrict__ gamma,
                      const float* __restrict__ beta,
                      float*       __restrict__ out,
                      int n_nodes, int n_edges)
{
    const int wave = threadIdx.x >> 6;
    const int lane = threadIdx.x & 63;
    const int q    = lane >> 4;
    const int sub  = lane & 15;
    const int node = blockIdx.x * WPB + wave;
    if (node >= n_nodes) return;

    const int start = row_ptr[node];
    const int end   = row_ptr[node + 1];
    const unsigned len = (unsigned)(end - start);

    float acc[8];
#pragma unroll
    for (int k = 0; k < 8; ++k) acc[k] = 0.f;

    const int ebase = start & ~3;
    for (int e0 = ebase; e0 < end; e0 += 4 * UF) {
        int   c[UF];
        float w[UF];
#pragma unroll
        for (int u = 0; u < UF; ++u) {
            int ei = e0 + 4 * u + q;                 // this lane's edge
            int eb = min(ei, n_edges - 1);           // clamp: never OOB
            bool in = (unsigned)(ei - start) < len;
            int   cc = edge_col[eb];                 // per-lane 4B load
            float ww = edge_val[eb];
            c[u] = in ? cc : 0;                      // masked -> hot row 0
            w[u] = in ? ww : 0.f;
        }
        uint4 v[UF];
#pragma unroll
        for (int u = 0; u < UF; ++u)
            v[u] = xh16[c[u] * (DIM / 8) + sub];     // 16B/lane gather
#pragma unroll
        for (int u = 0; u < UF; ++u) {
            const __half2* hp = (const __half2*)&v[u];
#pragma unroll
            for (int j = 0; j < 4; ++j) {
                float2 f = __half22float2(hp[j]);
                acc[2 * j]     = fmaf(w[u], f.x, acc[2 * j]);
                acc[2 * j + 1] = fmaf(w[u], f.y, acc[2 * j + 1]);
            }
        }
    }

    // fold the 4 quarter-waves (edge parities) into every lane
#pragma unroll
    for (int k = 0; k < 8; ++k) {
        acc[k] += __shfl_xor(acc[k], 16, 64);
        acc[k] += __shfl_xor(acc[k], 32, 64);
    }

    // residual from fp16 x
    uint4 xv = xh16[node * (DIM / 8) + sub];
    const __half2* xp = (const __half2*)&xv;
    float h[8];
#pragma unroll
    for (int j = 0; j < 4; ++j) {
        float2 f = __half22float2(xp[j]);
        h[2 * j]     = acc[2 * j]     + f.x;
        h[2 * j + 1] = acc[2 * j + 1] + f.y;
    }

    // layernorm stats: per-lane over 8 dims, then butterfly over sub (1,2,4,8)
    float s = 0.f, sq = 0.f;
#pragma unroll
    for (int k = 0; k < 8; ++k) { s += h[k]; sq += h[k] * h[k]; }
#pragma unroll
    for (int off = 1; off <= 8; off <<= 1) {
        s  += __shfl_xor(s,  off, 64);
        sq += __shfl_xor(sq, off, 64);
    }
    const float mean = s * (1.0f / (float)DIM);
    const float var  = sq * (1.0f / (float)DIM) - mean * mean;
    const float rs   = rsqrtf(var + EPS);

    // lane (q,sub) writes dims sub*8 + 2q + {0,1}  (512B contiguous per node)
    float hx = (q < 2) ? ((q == 0) ? h[0] : h[2]) : ((q == 2) ? h[4] : h[6]);
    float hy = (q < 2) ? ((q == 0) ? h[1] : h[3]) : ((q == 2) ? h[5] : h[7]);
    const int didx = sub * 4 + q;                    // float2 index in row
    const float2 g = ((const float2*)gamma)[didx];
    const float2 b = ((const float2*)beta)[didx];
    float2 o;
    o.x = (hx - mean) * rs * g.x + b.x;
    o.y = (hy - mean) * rs * g.y + b.y;
    ((float2*)out)[node * (DIM / 2) + didx] = o;
}

extern "C" void kernel_launch(void* const* d_in, const int* in_sizes, int n_in,
                              void* d_out, int out_size, void* d_ws, size_t ws_size,
                              hipStream_t stream)
{
    const float* x        = (const float*)d_in[0];
    const int*   edge_row = (const int*)  d_in[1];
    const int*   edge_col = (const int*)  d_in[2];
    const float* edge_val = (const float*)d_in[3];
    const float* gamma    = (const float*)d_in[4];
    const float* beta     = (const float*)d_in[5];
    float*       out      = (float*)d_out;

    const int n_nodes = in_sizes[0] / DIM;   // 100000
    const int n_edges = in_sizes[1];         // 3200000
    const int n_elem  = in_sizes[0];         // N*DIM
    const int n4      = n_elem / 4;

    // workspace: [x_half: n_elem*2 B][row_ptr: (n_nodes+1)*4 B]
    __half2* xh2     = (__half2*)d_ws;
    int*     row_ptr = (int*)((char*)d_ws + (size_t)n_elem * sizeof(__half));

    int prep_threads = (n4 > n_edges) ? n4 : n_edges;
    prep_kernel<<<(prep_threads + 255) / 256, 256, 0, stream>>>(
        (const float4*)x, xh2, edge_row, row_ptr, n4, n_nodes, n_edges);

    const int blocks = (n_nodes + WPB - 1) / WPB;
    gnn_fused_kernel<<<blocks, WPB * 64, 0, stream>>>(
        (const uint4*)d_ws, row_ptr, edge_col, edge_val, gamma, beta, out,
        n_nodes, n_edges);
}